// Round 3
// baseline (2692.422 us; speedup 1.0000x reference)
//
#include <hip/hip_runtime.h>
#include <hip/hip_bf16.h>

#define TT 200
#define NBATCH 256
#define HID 128
#define G4 512
#define VOC 50000

// R5/R6 design notes:
// - k2 was LDS-pipe-bound (model: phaseA 25x ds_read_b32 c-history + phaseB 16x
//   ds_read_b128 hsum broadcast per wave = ~7300 LDS-pipe cyc/step vs 2450 VALU).
//   Fix: c history -> registers (creg[25], symmetric with hreg); phase B octant
//   split (k-range 16 per wave -> 4x ds_read_b128), octant-sum folded into cell.
// - kxw was scalar-cache-latency-bound (uniform s_load of 128 ET rows/block).
//   Fix: vector-tiled GEMM, ET tile in LDS once, W coalesced float4, acc[8][4].
// - R6: resubmission of R5 (broker timeout, never measured). Audited: octant
//   algebra, barrier ledger, zero-init guard semantics, kxw tail block.

// ---------------- Kernel XW: XW = ET @ W + b  (50000 x 512) ----------------
// 512 thr: 32 rows x 512 cols per block. jq=tid&127 -> cols 4jq..4jq+3,
// rg=tid>>7 -> rows 8rg..8rg+8. ET tile (16KB) staged once, then pure compute.
__global__ __launch_bounds__(512) void kxw(
    const float* __restrict__ ET,       // (V, H)
    const float* __restrict__ W,        // (H, 4H)
    const float* __restrict__ b,        // (4H)
    float* __restrict__ XW)             // (V, 4H)
{
    const int tid = threadIdx.x;
    const int jq = tid & 127;
    const int j0 = jq * 4;
    const int rg = tid >> 7;            // 0..3, wave-uniform
    const int rb = blockIdx.x * 32;

    __shared__ __align__(16) float et[32][HID];   // 16 KB

    // stage ET tile: 4096 floats, thread loads 8 consecutive (2x float4)
    {
        const int bse = tid * 8;
        const int r = bse >> 7, c = bse & 127;
        int row = rb + r; row = row < VOC ? row : VOC - 1;
        const float4* src = (const float4*)(ET + (size_t)row * HID + c);
        float4 v0 = src[0], v1 = src[1];
        *((float4*)&et[r][c])     = v0;
        *((float4*)&et[r][c + 4]) = v1;
    }
    __syncthreads();

    float acc[8][4];
    #pragma unroll
    for (int r = 0; r < 8; ++r) {
        acc[r][0] = 0.f; acc[r][1] = 0.f; acc[r][2] = 0.f; acc[r][3] = 0.f;
    }

    const float4* W4 = (const float4*)W;     // W[k][j0..j0+3] = W4[k*128 + jq]
    #pragma unroll 2
    for (int k4 = 0; k4 < 32; ++k4) {
        const float4 w0 = W4[(size_t)(4 * k4 + 0) * 128 + jq];
        const float4 w1 = W4[(size_t)(4 * k4 + 1) * 128 + jq];
        const float4 w2 = W4[(size_t)(4 * k4 + 2) * 128 + jq];
        const float4 w3 = W4[(size_t)(4 * k4 + 3) * 128 + jq];
        #pragma unroll
        for (int r = 0; r < 8; ++r) {
            const float4 e4 = *(const float4*)&et[rg * 8 + r][4 * k4];  // broadcast
            acc[r][0] = fmaf(e4.x, w0.x, acc[r][0]);
            acc[r][0] = fmaf(e4.y, w1.x, acc[r][0]);
            acc[r][0] = fmaf(e4.z, w2.x, acc[r][0]);
            acc[r][0] = fmaf(e4.w, w3.x, acc[r][0]);
            acc[r][1] = fmaf(e4.x, w0.y, acc[r][1]);
            acc[r][1] = fmaf(e4.y, w1.y, acc[r][1]);
            acc[r][1] = fmaf(e4.z, w2.y, acc[r][1]);
            acc[r][1] = fmaf(e4.w, w3.y, acc[r][1]);
            acc[r][2] = fmaf(e4.x, w0.z, acc[r][2]);
            acc[r][2] = fmaf(e4.y, w1.z, acc[r][2]);
            acc[r][2] = fmaf(e4.z, w2.z, acc[r][2]);
            acc[r][2] = fmaf(e4.w, w3.z, acc[r][2]);
            acc[r][3] = fmaf(e4.x, w0.w, acc[r][3]);
            acc[r][3] = fmaf(e4.y, w1.w, acc[r][3]);
            acc[r][3] = fmaf(e4.z, w2.w, acc[r][3]);
            acc[r][3] = fmaf(e4.w, w3.w, acc[r][3]);
        }
    }

    const float4 bj = *(const float4*)&b[j0];
    #pragma unroll
    for (int r = 0; r < 8; ++r) {
        const int row = rb + rg * 8 + r;
        if (row < VOC) {
            float4 o;
            o.x = acc[r][0] + bj.x; o.y = acc[r][1] + bj.y;
            o.z = acc[r][2] + bj.z; o.w = acc[r][3] + bj.w;
            *(float4*)&XW[(size_t)row * G4 + j0] = o;
        }
    }
}

// ---------------- Kernel 2: recurrence, one 1024-thr block per n ----------------
// h AND c history in regs (hreg[25]/creg[25], group g=tid>>7 owns t' in
// [25g,25g+25)). Phase B octant-split: thread (g, c=tid&127) computes the 4 gate
// partials at column c over k in [16g,16g+16) -> 4x ds_read_b128 hsum broadcast
// per wave (was 16x); octant reduction folded into the cell phase (2 waves).
// 3 barriers/step. Prefetch (t+1 XW row + topo row) committed before bar C.
__global__ __launch_bounds__(1024) void k2_recur(
    const float* __restrict__ topo,     // (T, N, T)
    const float* __restrict__ mask,     // (T, N)
    const float* __restrict__ U,        // (H, 4H)
    const int*   __restrict__ seq,      // (T, N)
    const float* __restrict__ XW,       // (V, 4H)
    float* __restrict__ hmT)            // (H, N) transposed h_mean
{
    const int n   = blockIdx.x;
    const int tid = threadIdx.x;
    const int g   = __builtin_amdgcn_readfirstlane(tid >> 7);   // 0..7
    const int h   = tid & 127;

    __shared__ __align__(16) float topoS[2][8][32];   // double-buffered topo row
    __shared__ float part_h[8][HID];
    __shared__ float part_c[8][HID];
    __shared__ __align__(16) float hsum[HID];
    __shared__ float csum[HID];
    __shared__ float pBp[8][G4];                      // octant gate partials, 16KB
    __shared__ float xgl[2][G4];
    __shared__ int   seq_l[TT];
    __shared__ __align__(16) float mask_l[TT];

    // ucol[gate*16+kk] = U[16g+kk][gate*128+h]  (phase-B operand, 64 regs)
    float ucol[64];
    #pragma unroll
    for (int gate = 0; gate < 4; ++gate)
        #pragma unroll
        for (int kk = 0; kk < 16; ++kk)
            ucol[gate * 16 + kk] = U[(size_t)(16 * g + kk) * G4 + gate * 128 + h];

    float hreg[25], creg[25];
    #pragma unroll
    for (int k = 0; k < 25; ++k) { hreg[k] = 0.f; creg[k] = 0.f; }

    // one-time preload: per-n sequence + mask rows
    if (tid < TT) {
        seq_l[tid]  = seq[tid * NBATCH + n];
        mask_l[tid] = mask[tid * NBATCH + n];
    }
    // prologue stage for t=0
    if (tid < G4) {
        xgl[0][tid] = XW[(size_t)seq[n] * G4 + tid];
    } else if (tid < 768) {
        const int tt = tid - 512;
        const int gg = tt >> 5, ii = tt & 31;
        topoS[0][gg][ii] = (ii < 25)
            ? topo[(size_t)n * TT + 25 * gg + ii] : 0.f;   // t=0 row
    }

    float hmacc = 0.f;
    __syncthreads();

    for (int t = 0; t < TT; ++t) {
        const int cur = t & 1, nxt = cur ^ 1;

        // ---- issue prefetch for step t+1 (regs; committed before bar C) ----
        const int tn = (t + 1 < TT) ? t + 1 : t;
        float pf = 0.f;
        if (tid < G4) {
            pf = XW[(size_t)seq_l[tn] * G4 + tid];
        } else if (tid < 768) {
            const int tt = tid - 512;
            pf = ((tt & 31) < 25)
                ? topo[((size_t)tn * NBATCH + n) * TT + 25 * (tt >> 5) + (tt & 31)]
                : 0.f;
        }

        // ---- phase A: h and c partials, both from registers ----
        float ah0 = 0.f, ah1 = 0.f, ac0 = 0.f, ac1 = 0.f;
        const int base = 25 * g;
        const float4* tp4 = (const float4*)&topoS[cur][g][0];
        #pragma unroll
        for (int kk = 0; kk < 6; ++kk) {
            if (base + 4 * kk < t) {        // perf guard only; data is 0 beyond t
                float4 tp = tp4[kk];
                ah0 = fmaf(tp.x, hreg[4*kk+0], ah0);
                ac0 = fmaf(tp.x, creg[4*kk+0], ac0);
                ah1 = fmaf(tp.y, hreg[4*kk+1], ah1);
                ac1 = fmaf(tp.y, creg[4*kk+1], ac1);
                ah0 = fmaf(tp.z, hreg[4*kk+2], ah0);
                ac0 = fmaf(tp.z, creg[4*kk+2], ac0);
                ah1 = fmaf(tp.w, hreg[4*kk+3], ah1);
                ac1 = fmaf(tp.w, creg[4*kk+3], ac1);
            }
        }
        if (base + 24 < t) {
            const float tpl = topoS[cur][g][24];
            ah0 = fmaf(tpl, hreg[24], ah0);
            ac0 = fmaf(tpl, creg[24], ac0);
        }
        part_h[g][h] = ah0 + ah1;
        part_c[g][h] = ac0 + ac1;
        __syncthreads();                                        // (A)

        if (tid < HID) {
            float s = 0.f;
            #pragma unroll
            for (int gg = 0; gg < 8; ++gg) s += part_h[gg][tid];
            hsum[tid] = s;
        } else if (tid < 2 * HID) {
            const int hh = tid - HID;
            float s = 0.f;
            #pragma unroll
            for (int gg = 0; gg < 8; ++gg) s += part_c[gg][hh];
            csum[hh] = s;
        }
        __syncthreads();                                        // (B)

        // ---- phase B (octant): gates partial over k in [16g,16g+16) ----
        {
            const float4* hs4 = (const float4*)&hsum[16 * g];
            float a0 = 0.f, a1 = 0.f, a2 = 0.f, a3 = 0.f;
            #pragma unroll
            for (int q = 0; q < 4; ++q) {
                const float4 x = hs4[q];
                a0 = fmaf(x.x, ucol[ 0 + 4*q], a0);
                a0 = fmaf(x.y, ucol[ 1 + 4*q], a0);
                a0 = fmaf(x.z, ucol[ 2 + 4*q], a0);
                a0 = fmaf(x.w, ucol[ 3 + 4*q], a0);
                a1 = fmaf(x.x, ucol[16 + 4*q], a1);
                a1 = fmaf(x.y, ucol[17 + 4*q], a1);
                a1 = fmaf(x.z, ucol[18 + 4*q], a1);
                a1 = fmaf(x.w, ucol[19 + 4*q], a1);
                a2 = fmaf(x.x, ucol[32 + 4*q], a2);
                a2 = fmaf(x.y, ucol[33 + 4*q], a2);
                a2 = fmaf(x.z, ucol[34 + 4*q], a2);
                a2 = fmaf(x.w, ucol[35 + 4*q], a2);
                a3 = fmaf(x.x, ucol[48 + 4*q], a3);
                a3 = fmaf(x.y, ucol[49 + 4*q], a3);
                a3 = fmaf(x.z, ucol[50 + 4*q], a3);
                a3 = fmaf(x.w, ucol[51 + 4*q], a3);
            }
            pBp[g][      h] = a0;
            pBp[g][128 + h] = a1;
            pBp[g][256 + h] = a2;
            pBp[g][384 + h] = a3;
        }
        // commit prefetch to the nxt buffers (next phase A separated by bar C)
        if (tid < G4) {
            xgl[nxt][tid] = pf;
        } else if (tid < 768) {
            const int tt = tid - 512;
            topoS[nxt][tt >> 5][tt & 31] = pf;
        }
        __syncthreads();                                        // (C)

        // ---- cell: owning group g* = t/25; octant-sum folded in ----
        const int gstar = t / 25;
        if (g == gstar) {
            const float m = mask_l[t];
            float iv = xgl[cur][      h];
            float fv = xgl[cur][128 + h];
            float ov = xgl[cur][256 + h];
            float gv = xgl[cur][384 + h];
            #pragma unroll
            for (int o = 0; o < 8; ++o) {
                iv += pBp[o][      h];
                fv += pBp[o][128 + h];
                ov += pBp[o][256 + h];
                gv += pBp[o][384 + h];
            }
            const float si = 1.f / (1.f + expf(-iv));
            const float sf = 1.f / (1.f + expf(-fv));
            const float so = 1.f / (1.f + expf(-ov));
            const float tg = tanhf(gv);
            const float cn = m * (sf * csum[h] + si * tg);
            const float hn = m * (so * tanhf(cn));
            const int kt = t - 25 * gstar;
            #pragma unroll
            for (int k = 0; k < 25; ++k) if (k == kt) { hreg[k] = hn; creg[k] = cn; }
            hmacc = fmaf(m, hn, hmacc);
        }
        // hazards: topoS[nxt]/xgl[nxt] written before bar C, read next phase A /
        // next cell; pBp rewritten next phase B (>=2 bars after cell read);
        // hsum/csum rewritten next reduce (>=1 bar after their reads).
    }

    part_h[g][h] = hmacc;     // unique slot per thread
    __syncthreads();
    if (tid < HID) {
        float s = 0.f;
        #pragma unroll
        for (int gg = 0; gg < 8; ++gg) s += part_h[gg][tid];
        float len = 0.f;
        const float4* m4 = (const float4*)mask_l;
        #pragma unroll 10
        for (int q = 0; q < TT / 4; ++q) {
            const float4 mm = m4[q];
            len += (mm.x + mm.y) + (mm.z + mm.w);
        }
        hmT[(size_t)tid * NBATCH + n] = s / len;   // transposed for k3
    }
}

// ---------------- Kernel 3: out = h_mean @ W_out + b_out  (k-outer matvec) ----------------
// 512 thr: v = column; acc[32] rows; Wout coalesced, hmT row-slice via s_load.
__global__ __launch_bounds__(512) void k3_out(
    const float* __restrict__ hmT,     // (H, N)
    const float* __restrict__ Wout,    // (H, V)
    const float* __restrict__ bout,    // (V)
    float* __restrict__ out)           // (N, V)
{
    const int tid = threadIdx.x;
    const int v = blockIdx.x * 512 + tid;
    const int r0 = blockIdx.y * 32;
    const int vc = v < VOC ? v : VOC - 1;

    float acc[32];
    #pragma unroll
    for (int r = 0; r < 32; ++r) acc[r] = 0.f;

    #pragma unroll 2
    for (int k = 0; k < HID; ++k) {
        const float wv = Wout[(size_t)k * VOC + vc];   // coalesced vector load
        const float* hr = hmT + k * NBATCH + r0;       // uniform -> s_load
        #pragma unroll
        for (int r = 0; r < 32; ++r) acc[r] = fmaf(hr[r], wv, acc[r]);
    }
    const float bv = bout[vc];
    if (v < VOC) {
        for (int r = 0; r < 32; ++r)
            out[(size_t)(r0 + r) * VOC + v] = acc[r] + bv;
    }
}

extern "C" void kernel_launch(void* const* d_in, const int* in_sizes, int n_in,
                              void* d_out, int out_size, void* d_ws, size_t ws_size,
                              hipStream_t stream) {
    const int*   seq  = (const int*)d_in[0];     // (T,N) int32
    const float* msk  = (const float*)d_in[1];   // (T,N)
    const float* topo = (const float*)d_in[2];   // (T,N,T)
    const float* W    = (const float*)d_in[3];   // (H,4H)
    const float* U    = (const float*)d_in[4];   // (H,4H)
    const float* b    = (const float*)d_in[5];   // (4H)
    const float* ET   = (const float*)d_in[6];   // (V,H)
    const float* Wout = (const float*)d_in[7];   // (H,V)
    const float* bout = (const float*)d_in[8];   // (V)
    float* out = (float*)d_out;

    float* XW  = (float*)d_ws;                                   // 102.4 MB
    float* hmT = (float*)((char*)d_ws + (size_t)VOC * G4 * sizeof(float)); // +128 KB

    kxw<<<(VOC + 31) / 32, 512, 0, stream>>>(ET, W, b, XW);
    k2_recur<<<NBATCH, 1024, 0, stream>>>(topo, msk, U, seq, XW, hmT);
    k3_out<<<dim3(98, 8), 512, 0, stream>>>(hmT, Wout, bout, out);
}

// Round 4
// 2620.476 us; speedup vs baseline: 1.0275x; 1.0275x over previous
//
#include <hip/hip_runtime.h>
#include <hip/hip_bf16.h>

#define TT 200
#define NBATCH 256
#define HID 128
#define G4 512
#define VOC 50000

// R7 design notes (post-mortem of R6's 3.5x regression):
// - R6 put c-history in registers -> persistent regs 114 (+temps) > 128 budget
//   (64 VGPR + 64 AGPR at 4 waves/SIMD) -> per-step scratch spill/fill ->
//   FETCH_SIZE 81MB -> 3.34GB, k2 677 -> 2407 us. Registers are NOT free here.
// - R7 = R4's measured-clean register footprint (ucol 64 + hreg 25 = 89) with
//   c-history back in LDS (c_lds[128][209], measured 0 bank conflicts), KEEPING
//   the octant phase B (4x ds_read_b128/wave instead of 16x; register-neutral).
// - Cycle model from measured R4 step (8100 cyc): -2300 (phase B LDS) +370
//   (octant sum in cell, 2 waves) -> ~6100 cyc/step -> k2 ~510 us.

// ---------------- Kernel XW: XW = ET @ W + b  (50000 x 512) ----------------
// 512 thr: 32 rows x 512 cols per block. jq=tid&127 -> cols 4jq..4jq+3,
// rg=tid>>7 -> rows 8rg..8rg+8. ET tile (16KB) staged once, then pure compute.
__global__ __launch_bounds__(512) void kxw(
    const float* __restrict__ ET,       // (V, H)
    const float* __restrict__ W,        // (H, 4H)
    const float* __restrict__ b,        // (4H)
    float* __restrict__ XW)             // (V, 4H)
{
    const int tid = threadIdx.x;
    const int jq = tid & 127;
    const int j0 = jq * 4;
    const int rg = tid >> 7;            // 0..3, wave-uniform
    const int rb = blockIdx.x * 32;

    __shared__ __align__(16) float et[32][HID];   // 16 KB

    // stage ET tile: 4096 floats, thread loads 8 consecutive (2x float4)
    {
        const int bse = tid * 8;
        const int r = bse >> 7, c = bse & 127;
        int row = rb + r; row = row < VOC ? row : VOC - 1;
        const float4* src = (const float4*)(ET + (size_t)row * HID + c);
        float4 v0 = src[0], v1 = src[1];
        *((float4*)&et[r][c])     = v0;
        *((float4*)&et[r][c + 4]) = v1;
    }
    __syncthreads();

    float acc[8][4];
    #pragma unroll
    for (int r = 0; r < 8; ++r) {
        acc[r][0] = 0.f; acc[r][1] = 0.f; acc[r][2] = 0.f; acc[r][3] = 0.f;
    }

    const float4* W4 = (const float4*)W;     // W[k][j0..j0+3] = W4[k*128 + jq]
    #pragma unroll 2
    for (int k4 = 0; k4 < 32; ++k4) {
        const float4 w0 = W4[(size_t)(4 * k4 + 0) * 128 + jq];
        const float4 w1 = W4[(size_t)(4 * k4 + 1) * 128 + jq];
        const float4 w2 = W4[(size_t)(4 * k4 + 2) * 128 + jq];
        const float4 w3 = W4[(size_t)(4 * k4 + 3) * 128 + jq];
        #pragma unroll
        for (int r = 0; r < 8; ++r) {
            const float4 e4 = *(const float4*)&et[rg * 8 + r][4 * k4];  // broadcast
            acc[r][0] = fmaf(e4.x, w0.x, acc[r][0]);
            acc[r][0] = fmaf(e4.y, w1.x, acc[r][0]);
            acc[r][0] = fmaf(e4.z, w2.x, acc[r][0]);
            acc[r][0] = fmaf(e4.w, w3.x, acc[r][0]);
            acc[r][1] = fmaf(e4.x, w0.y, acc[r][1]);
            acc[r][1] = fmaf(e4.y, w1.y, acc[r][1]);
            acc[r][1] = fmaf(e4.z, w2.y, acc[r][1]);
            acc[r][1] = fmaf(e4.w, w3.y, acc[r][1]);
            acc[r][2] = fmaf(e4.x, w0.z, acc[r][2]);
            acc[r][2] = fmaf(e4.y, w1.z, acc[r][2]);
            acc[r][2] = fmaf(e4.z, w2.z, acc[r][2]);
            acc[r][2] = fmaf(e4.w, w3.z, acc[r][2]);
            acc[r][3] = fmaf(e4.x, w0.w, acc[r][3]);
            acc[r][3] = fmaf(e4.y, w1.w, acc[r][3]);
            acc[r][3] = fmaf(e4.z, w2.w, acc[r][3]);
            acc[r][3] = fmaf(e4.w, w3.w, acc[r][3]);
        }
    }

    const float4 bj = *(const float4*)&b[j0];
    #pragma unroll
    for (int r = 0; r < 8; ++r) {
        const int row = rb + rg * 8 + r;
        if (row < VOC) {
            float4 o;
            o.x = acc[r][0] + bj.x; o.y = acc[r][1] + bj.y;
            o.z = acc[r][2] + bj.z; o.w = acc[r][3] + bj.w;
            *(float4*)&XW[(size_t)row * G4 + j0] = o;
        }
    }
}

// ---------------- Kernel 2: recurrence, one 1024-thr block per n ----------------
// h history in regs (hreg[25], group g=tid>>7 owns t' in [25g,25g+25)),
// c history in LDS (c_lds[h][209], pad 209 -> conflict-free, same-thread RW).
// Phase B octant-split: thread (g, h) computes 4 gate partials at column h over
// k in [16g,16g+16) -> 4x ds_read_b128 hsum broadcast per wave (was 16x);
// octant reduction folded into the cell phase (2 waves, no extra barrier).
// 3 barriers/step. Prefetch (t+1 XW row + topo row) committed before bar C.
// Persistent regs: ucol 64 + hreg 25 = 89 (R4-measured clean; NO creg -> no spill).
__global__ __launch_bounds__(1024) void k2_recur(
    const float* __restrict__ topo,     // (T, N, T)
    const float* __restrict__ mask,     // (T, N)
    const float* __restrict__ U,        // (H, 4H)
    const int*   __restrict__ seq,      // (T, N)
    const float* __restrict__ XW,       // (V, 4H)
    float* __restrict__ hmT)            // (H, N) transposed h_mean
{
    const int n   = blockIdx.x;
    const int tid = threadIdx.x;
    const int g   = __builtin_amdgcn_readfirstlane(tid >> 7);   // 0..7
    const int h   = tid & 127;

    __shared__ float c_lds[HID][209];                 // 104.5 KB, c_lds[h][t']
    __shared__ __align__(16) float topoS[2][8][32];   // double-buffered topo row
    __shared__ float part_h[8][HID];
    __shared__ float part_c[8][HID];
    __shared__ __align__(16) float hsum[HID];
    __shared__ float csum[HID];
    __shared__ float pBp[8][G4];                      // octant gate partials, 16KB
    __shared__ float xgl[2][G4];
    __shared__ int   seq_l[TT];
    __shared__ __align__(16) float mask_l[TT];

    // ucol[gate*16+kk] = U[16g+kk][gate*128+h]  (phase-B operand, 64 regs)
    float ucol[64];
    #pragma unroll
    for (int gate = 0; gate < 4; ++gate)
        #pragma unroll
        for (int kk = 0; kk < 16; ++kk)
            ucol[gate * 16 + kk] = U[(size_t)(16 * g + kk) * G4 + gate * 128 + h];

    float hreg[25];
    #pragma unroll
    for (int k = 0; k < 25; ++k) hreg[k] = 0.f;
    for (int i = tid; i < HID * 209; i += 1024) (&c_lds[0][0])[i] = 0.f;

    // one-time preload: per-n sequence + mask rows
    if (tid < TT) {
        seq_l[tid]  = seq[tid * NBATCH + n];
        mask_l[tid] = mask[tid * NBATCH + n];
    }
    // prologue stage for t=0
    if (tid < G4) {
        xgl[0][tid] = XW[(size_t)seq[n] * G4 + tid];
    } else if (tid < 768) {
        const int tt = tid - 512;
        const int gg = tt >> 5, ii = tt & 31;
        topoS[0][gg][ii] = (ii < 25)
            ? topo[(size_t)n * TT + 25 * gg + ii] : 0.f;   // t=0 row
    }

    float hmacc = 0.f;
    __syncthreads();

    for (int t = 0; t < TT; ++t) {
        const int cur = t & 1, nxt = cur ^ 1;

        // ---- issue prefetch for step t+1 (regs; committed before bar C) ----
        const int tn = (t + 1 < TT) ? t + 1 : t;
        float pf = 0.f;
        if (tid < G4) {
            pf = XW[(size_t)seq_l[tn] * G4 + tid];
        } else if (tid < 768) {
            const int tt = tid - 512;
            pf = ((tt & 31) < 25)
                ? topo[((size_t)tn * NBATCH + n) * TT + 25 * (tt >> 5) + (tt & 31)]
                : 0.f;
        }

        // ---- phase A: h partial from regs, c partial from LDS ----
        float ah0 = 0.f, ah1 = 0.f, ac0 = 0.f, ac1 = 0.f;
        const int base = 25 * g;
        const float4* tp4 = (const float4*)&topoS[cur][g][0];
        const float* crow = &c_lds[h][0];
        #pragma unroll
        for (int kk = 0; kk < 6; ++kk) {
            if (base + 4 * kk < t) {        // perf guard only; data is 0 beyond t
                float4 tp = tp4[kk];
                ah0 = fmaf(tp.x, hreg[4*kk+0], ah0);
                ac0 = fmaf(tp.x, crow[base+4*kk+0], ac0);
                ah1 = fmaf(tp.y, hreg[4*kk+1], ah1);
                ac1 = fmaf(tp.y, crow[base+4*kk+1], ac1);
                ah0 = fmaf(tp.z, hreg[4*kk+2], ah0);
                ac0 = fmaf(tp.z, crow[base+4*kk+2], ac0);
                ah1 = fmaf(tp.w, hreg[4*kk+3], ah1);
                ac1 = fmaf(tp.w, crow[base+4*kk+3], ac1);
            }
        }
        if (base + 24 < t) {
            const float tpl = topoS[cur][g][24];
            ah0 = fmaf(tpl, hreg[24], ah0);
            ac0 = fmaf(tpl, crow[base+24], ac0);
        }
        part_h[g][h] = ah0 + ah1;
        part_c[g][h] = ac0 + ac1;
        __syncthreads();                                        // (A)

        if (tid < HID) {
            float s = 0.f;
            #pragma unroll
            for (int gg = 0; gg < 8; ++gg) s += part_h[gg][tid];
            hsum[tid] = s;
        } else if (tid < 2 * HID) {
            const int hh = tid - HID;
            float s = 0.f;
            #pragma unroll
            for (int gg = 0; gg < 8; ++gg) s += part_c[gg][hh];
            csum[hh] = s;
        }
        __syncthreads();                                        // (B)

        // ---- phase B (octant): gates partial over k in [16g,16g+16) ----
        {
            const float4* hs4 = (const float4*)&hsum[16 * g];
            float a0 = 0.f, a1 = 0.f, a2 = 0.f, a3 = 0.f;
            #pragma unroll
            for (int q = 0; q < 4; ++q) {
                const float4 x = hs4[q];
                a0 = fmaf(x.x, ucol[ 0 + 4*q], a0);
                a0 = fmaf(x.y, ucol[ 1 + 4*q], a0);
                a0 = fmaf(x.z, ucol[ 2 + 4*q], a0);
                a0 = fmaf(x.w, ucol[ 3 + 4*q], a0);
                a1 = fmaf(x.x, ucol[16 + 4*q], a1);
                a1 = fmaf(x.y, ucol[17 + 4*q], a1);
                a1 = fmaf(x.z, ucol[18 + 4*q], a1);
                a1 = fmaf(x.w, ucol[19 + 4*q], a1);
                a2 = fmaf(x.x, ucol[32 + 4*q], a2);
                a2 = fmaf(x.y, ucol[33 + 4*q], a2);
                a2 = fmaf(x.z, ucol[34 + 4*q], a2);
                a2 = fmaf(x.w, ucol[35 + 4*q], a2);
                a3 = fmaf(x.x, ucol[48 + 4*q], a3);
                a3 = fmaf(x.y, ucol[49 + 4*q], a3);
                a3 = fmaf(x.z, ucol[50 + 4*q], a3);
                a3 = fmaf(x.w, ucol[51 + 4*q], a3);
            }
            pBp[g][      h] = a0;
            pBp[g][128 + h] = a1;
            pBp[g][256 + h] = a2;
            pBp[g][384 + h] = a3;
        }
        // commit prefetch to the nxt buffers (next phase A separated by bar C)
        if (tid < G4) {
            xgl[nxt][tid] = pf;
        } else if (tid < 768) {
            const int tt = tid - 512;
            topoS[nxt][tt >> 5][tt & 31] = pf;
        }
        __syncthreads();                                        // (C)

        // ---- cell: owning group g* = t/25; octant-sum folded in ----
        const int gstar = t / 25;
        if (g == gstar) {
            const float m = mask_l[t];
            float iv = xgl[cur][      h];
            float fv = xgl[cur][128 + h];
            float ov = xgl[cur][256 + h];
            float gv = xgl[cur][384 + h];
            #pragma unroll
            for (int o = 0; o < 8; ++o) {
                iv += pBp[o][      h];
                fv += pBp[o][128 + h];
                ov += pBp[o][256 + h];
                gv += pBp[o][384 + h];
            }
            const float si = 1.f / (1.f + expf(-iv));
            const float sf = 1.f / (1.f + expf(-fv));
            const float so = 1.f / (1.f + expf(-ov));
            const float tg = tanhf(gv);
            const float cn = m * (sf * csum[h] + si * tg);
            const float hn = m * (so * tanhf(cn));
            const int kt = t - 25 * gstar;
            #pragma unroll
            for (int k = 0; k < 25; ++k) if (k == kt) hreg[k] = hn;
            c_lds[h][t] = cn;   // only group g* reads [h][25g*..): same-thread RW
            hmacc = fmaf(m, hn, hmacc);
        }
        // hazards: topoS[nxt]/xgl[nxt] written before bar C, read next phase A /
        // next cell; pBp rewritten next phase B (bars A,B after cell read);
        // hsum/csum rewritten next reduce (bar >=1 after their reads).
    }

    part_h[g][h] = hmacc;     // unique slot per thread
    __syncthreads();
    if (tid < HID) {
        float s = 0.f;
        #pragma unroll
        for (int gg = 0; gg < 8; ++gg) s += part_h[gg][tid];
        float len = 0.f;
        const float4* m4 = (const float4*)mask_l;
        #pragma unroll 10
        for (int q = 0; q < TT / 4; ++q) {
            const float4 mm = m4[q];
            len += (mm.x + mm.y) + (mm.z + mm.w);
        }
        hmT[(size_t)tid * NBATCH + n] = s / len;   // transposed for k3
    }
}

// ---------------- Kernel 3: out = h_mean @ W_out + b_out  (k-outer matvec) ----------------
// 512 thr: v = column; acc[32] rows; Wout coalesced, hmT row-slice via s_load.
__global__ __launch_bounds__(512) void k3_out(
    const float* __restrict__ hmT,     // (H, N)
    const float* __restrict__ Wout,    // (H, V)
    const float* __restrict__ bout,    // (V)
    float* __restrict__ out)           // (N, V)
{
    const int tid = threadIdx.x;
    const int v = blockIdx.x * 512 + tid;
    const int r0 = blockIdx.y * 32;
    const int vc = v < VOC ? v : VOC - 1;

    float acc[32];
    #pragma unroll
    for (int r = 0; r < 32; ++r) acc[r] = 0.f;

    #pragma unroll 2
    for (int k = 0; k < HID; ++k) {
        const float wv = Wout[(size_t)k * VOC + vc];   // coalesced vector load
        const float* hr = hmT + k * NBATCH + r0;       // uniform -> s_load
        #pragma unroll
        for (int r = 0; r < 32; ++r) acc[r] = fmaf(hr[r], wv, acc[r]);
    }
    const float bv = bout[vc];
    if (v < VOC) {
        for (int r = 0; r < 32; ++r)
            out[(size_t)(r0 + r) * VOC + v] = acc[r] + bv;
    }
}

extern "C" void kernel_launch(void* const* d_in, const int* in_sizes, int n_in,
                              void* d_out, int out_size, void* d_ws, size_t ws_size,
                              hipStream_t stream) {
    const int*   seq  = (const int*)d_in[0];     // (T,N) int32
    const float* msk  = (const float*)d_in[1];   // (T,N)
    const float* topo = (const float*)d_in[2];   // (T,N,T)
    const float* W    = (const float*)d_in[3];   // (H,4H)
    const float* U    = (const float*)d_in[4];   // (H,4H)
    const float* b    = (const float*)d_in[5];   // (4H)
    const float* ET   = (const float*)d_in[6];   // (V,H)
    const float* Wout = (const float*)d_in[7];   // (H,V)
    const float* bout = (const float*)d_in[8];   // (V)
    float* out = (float*)d_out;

    float* XW  = (float*)d_ws;                                   // 102.4 MB
    float* hmT = (float*)((char*)d_ws + (size_t)VOC * G4 * sizeof(float)); // +128 KB

    kxw<<<(VOC + 31) / 32, 512, 0, stream>>>(ET, W, b, XW);
    k2_recur<<<NBATCH, 1024, 0, stream>>>(topo, msk, U, seq, XW, hmT);
    k3_out<<<dim3(98, 8), 512, 0, stream>>>(hmT, Wout, bout, out);
}

// Round 5
// 916.638 us; speedup vs baseline: 2.9373x; 2.8588x over previous
//
#include <hip/hip_runtime.h>
#include <hip/hip_bf16.h>

#define TT 200
#define NBATCH 256
#define HID 128
#define G4 512
#define VOC 50000

// R8 design notes:
// - R6/R7 post-mortem: octant phase-B restructure (regrouped ucol + pBp[8][512]
//   + 36-live cell octant-sum) makes the allocator demote ~16 ucol regs to
//   scratch -> read-refill every step -> FETCH 81MB->3.38GB, k2 677->2360 us.
//   Signature: reads +3.3GB, writes only +29MB = read-only spill refill.
// - R8: k2 reverted EXACTLY to the R1-measured 677us text (VGPR 64, FETCH 81MB,
//   0 bank conflicts). kxw kept at the R5 vector-tiled version (measured: non-k2
//   time 405 -> ~260 us). k3 unchanged.
// - Banked negative result: c_lds[h][209] scalar b32 reads are conflict-free
//   (~145 cyc/wave); float4-izing them needs alignment that causes 16-way
//   conflicts (or a swizzle that nets ~0). Do not "vectorize" c-history.

// ---------------- Kernel XW: XW = ET @ W + b  (50000 x 512) ----------------
// 512 thr: 32 rows x 512 cols per block. jq=tid&127 -> cols 4jq..4jq+3,
// rg=tid>>7 -> rows 8rg..8rg+8. ET tile (16KB) staged once, then pure compute.
__global__ __launch_bounds__(512) void kxw(
    const float* __restrict__ ET,       // (V, H)
    const float* __restrict__ W,        // (H, 4H)
    const float* __restrict__ b,        // (4H)
    float* __restrict__ XW)             // (V, 4H)
{
    const int tid = threadIdx.x;
    const int jq = tid & 127;
    const int j0 = jq * 4;
    const int rg = tid >> 7;            // 0..3, wave-uniform
    const int rb = blockIdx.x * 32;

    __shared__ __align__(16) float et[32][HID];   // 16 KB

    // stage ET tile: 4096 floats, thread loads 8 consecutive (2x float4)
    {
        const int bse = tid * 8;
        const int r = bse >> 7, c = bse & 127;
        int row = rb + r; row = row < VOC ? row : VOC - 1;
        const float4* src = (const float4*)(ET + (size_t)row * HID + c);
        float4 v0 = src[0], v1 = src[1];
        *((float4*)&et[r][c])     = v0;
        *((float4*)&et[r][c + 4]) = v1;
    }
    __syncthreads();

    float acc[8][4];
    #pragma unroll
    for (int r = 0; r < 8; ++r) {
        acc[r][0] = 0.f; acc[r][1] = 0.f; acc[r][2] = 0.f; acc[r][3] = 0.f;
    }

    const float4* W4 = (const float4*)W;     // W[k][j0..j0+3] = W4[k*128 + jq]
    #pragma unroll 2
    for (int k4 = 0; k4 < 32; ++k4) {
        const float4 w0 = W4[(size_t)(4 * k4 + 0) * 128 + jq];
        const float4 w1 = W4[(size_t)(4 * k4 + 1) * 128 + jq];
        const float4 w2 = W4[(size_t)(4 * k4 + 2) * 128 + jq];
        const float4 w3 = W4[(size_t)(4 * k4 + 3) * 128 + jq];
        #pragma unroll
        for (int r = 0; r < 8; ++r) {
            const float4 e4 = *(const float4*)&et[rg * 8 + r][4 * k4];  // broadcast
            acc[r][0] = fmaf(e4.x, w0.x, acc[r][0]);
            acc[r][0] = fmaf(e4.y, w1.x, acc[r][0]);
            acc[r][0] = fmaf(e4.z, w2.x, acc[r][0]);
            acc[r][0] = fmaf(e4.w, w3.x, acc[r][0]);
            acc[r][1] = fmaf(e4.x, w0.y, acc[r][1]);
            acc[r][1] = fmaf(e4.y, w1.y, acc[r][1]);
            acc[r][1] = fmaf(e4.z, w2.y, acc[r][1]);
            acc[r][1] = fmaf(e4.w, w3.y, acc[r][1]);
            acc[r][2] = fmaf(e4.x, w0.z, acc[r][2]);
            acc[r][2] = fmaf(e4.y, w1.z, acc[r][2]);
            acc[r][2] = fmaf(e4.z, w2.z, acc[r][2]);
            acc[r][2] = fmaf(e4.w, w3.z, acc[r][2]);
            acc[r][3] = fmaf(e4.x, w0.w, acc[r][3]);
            acc[r][3] = fmaf(e4.y, w1.w, acc[r][3]);
            acc[r][3] = fmaf(e4.z, w2.w, acc[r][3]);
            acc[r][3] = fmaf(e4.w, w3.w, acc[r][3]);
        }
    }

    const float4 bj = *(const float4*)&b[j0];
    #pragma unroll
    for (int r = 0; r < 8; ++r) {
        const int row = rb + rg * 8 + r;
        if (row < VOC) {
            float4 o;
            o.x = acc[r][0] + bj.x; o.y = acc[r][1] + bj.y;
            o.z = acc[r][2] + bj.z; o.w = acc[r][3] + bj.w;
            *(float4*)&XW[(size_t)row * G4 + j0] = o;
        }
    }
}

// ---------------- Kernel 2: recurrence, one 1024-thr block per n ----------------
// EXACT R1-measured 677us text. h history in regs (hreg[25], group g=tid>>7 owns
// rows [25g,25g+25)), c history in LDS (c_lds[h][209], pad 209 -> conflict-free),
// U in regs (ucol[64], K-half kh=tid>>9). seq/mask preloaded to LDS once;
// XW row + topo row for step t+1 prefetched into REGISTERS at the top of step t
// (threads 0-511 XW, 512-767 topo -> disjoint, parallel issue) and committed to
// the double-buffered LDS slots in the phase-B region (before barrier C).
// 3 barriers/step.
__global__ __launch_bounds__(1024) void k2_recur(
    const float* __restrict__ topo,     // (T, N, T)
    const float* __restrict__ mask,     // (T, N)
    const float* __restrict__ U,        // (H, 4H)
    const int*   __restrict__ seq,      // (T, N)
    const float* __restrict__ XW,       // (V, 4H)
    float* __restrict__ hmT)            // (H, N) transposed h_mean
{
    const int n   = blockIdx.x;
    const int tid = threadIdx.x;
    const int g   = __builtin_amdgcn_readfirstlane(tid >> 7);   // 0..7
    const int h   = tid & 127;
    const int kh  = __builtin_amdgcn_readfirstlane(tid >> 9);   // 0..1
    const int j   = tid & 511;

    __shared__ float c_lds[HID][209];                 // 104.5 KB, c_lds[h][t']
    __shared__ __align__(16) float topoS[2][8][32];   // double-buffered topo row
    __shared__ float part_h[8][HID];
    __shared__ float part_c[8][HID];
    __shared__ __align__(16) float hsum[HID];
    __shared__ float csum[HID];
    __shared__ float pB[2][G4];
    __shared__ float xgl[2][G4];
    __shared__ int   seq_l[TT];
    __shared__ float mask_l[TT];

    float ucol[64];
    #pragma unroll
    for (int kk = 0; kk < 64; ++kk) ucol[kk] = U[(size_t)(kh * 64 + kk) * G4 + j];

    float hreg[25];
    #pragma unroll
    for (int k = 0; k < 25; ++k) hreg[k] = 0.f;
    for (int i = tid; i < HID * 209; i += 1024) (&c_lds[0][0])[i] = 0.f;

    // one-time preload: per-n sequence + mask rows (kills per-step s_load chain)
    if (tid < TT) {
        seq_l[tid]  = seq[tid * NBATCH + n];
        mask_l[tid] = mask[tid * NBATCH + n];
    }
    // prologue stage for t=0 (addresses straight from global, uniform)
    if (tid < G4) {
        xgl[0][tid] = XW[(size_t)seq[n] * G4 + tid];
    } else if (tid < 768) {
        const int tt = tid - 512;
        const int gg = tt >> 5, ii = tt & 31;
        topoS[0][gg][ii] = (ii < 25)
            ? topo[(size_t)n * TT + 25 * gg + ii] : 0.f;   // t=0 row
    }

    float hmacc = 0.f, len = 0.f;
    __syncthreads();

    for (int t = 0; t < TT; ++t) {
        const int cur = t & 1, nxt = cur ^ 1;

        // ---- issue prefetch for step t+1 (registers; committed before bar C) ----
        const int tn = (t + 1 < TT) ? t + 1 : t;
        float pf = 0.f;
        if (tid < G4) {
            pf = XW[(size_t)seq_l[tn] * G4 + tid];
        } else if (tid < 768) {
            const int tt = tid - 512;
            const int gg = tt >> 5, ii = tt & 31;
            pf = (ii < 25)
                ? topo[((size_t)tn * NBATCH + n) * TT + 25 * gg + ii] : 0.f;
        }
        const float m = mask_l[t];

        // ---- phase A: h partial from regs, c partial from LDS ----
        float ah0 = 0.f, ah1 = 0.f, ac0 = 0.f, ac1 = 0.f;
        const int base = 25 * g;
        const float4* tp4 = (const float4*)&topoS[cur][g][0];
        const float* crow = &c_lds[h][0];
        #pragma unroll
        for (int kk = 0; kk < 6; ++kk) {
            if (base + 4 * kk < t) {        // perf guard only; data is 0 beyond t
                float4 tp = tp4[kk];
                ah0 = fmaf(tp.x, hreg[4*kk+0], ah0);
                ac0 = fmaf(tp.x, crow[base+4*kk+0], ac0);
                ah1 = fmaf(tp.y, hreg[4*kk+1], ah1);
                ac1 = fmaf(tp.y, crow[base+4*kk+1], ac1);
                ah0 = fmaf(tp.z, hreg[4*kk+2], ah0);
                ac0 = fmaf(tp.z, crow[base+4*kk+2], ac0);
                ah1 = fmaf(tp.w, hreg[4*kk+3], ah1);
                ac1 = fmaf(tp.w, crow[base+4*kk+3], ac1);
            }
        }
        if (base + 24 < t) {
            const float tpl = topoS[cur][g][24];
            ah0 = fmaf(tpl, hreg[24], ah0);
            ac0 = fmaf(tpl, crow[base+24], ac0);
        }
        part_h[g][h] = ah0 + ah1;
        part_c[g][h] = ac0 + ac1;
        __syncthreads();                                        // (A)

        if (tid < HID) {
            float s = 0.f;
            #pragma unroll
            for (int gg = 0; gg < 8; ++gg) s += part_h[gg][tid];
            hsum[tid] = s;
        } else if (tid < 2 * HID) {
            const int hh = tid - HID;
            float s = 0.f;
            #pragma unroll
            for (int gg = 0; gg < 8; ++gg) s += part_c[gg][hh];
            csum[hh] = s;
        }
        __syncthreads();                                        // (B)

        // ---- phase B: pB[kh][j] = hsum[kh-half] . U-half column ----
        {
            float a0 = 0.f, a1 = 0.f, a2 = 0.f, a3 = 0.f;
            const float4* hs4 = (const float4*)&hsum[kh * 64];
            #pragma unroll
            for (int q = 0; q < 16; ++q) {
                float4 x = hs4[q];
                a0 = fmaf(x.x, ucol[4*q+0], a0);
                a1 = fmaf(x.y, ucol[4*q+1], a1);
                a2 = fmaf(x.z, ucol[4*q+2], a2);
                a3 = fmaf(x.w, ucol[4*q+3], a3);
            }
            pB[kh][j] = (a0 + a1) + (a2 + a3);
        }
        // commit prefetch to the nxt buffers (separated from next phase A by bar C)
        if (tid < G4) {
            xgl[nxt][tid] = pf;
        } else if (tid < 768) {
            const int tt = tid - 512;
            topoS[nxt][tt >> 5][tt & 31] = pf;
        }
        __syncthreads();                                        // (C)

        // ---- cell: owning group g* = t/25 (wave-uniform branch) ----
        const int gstar = t / 25;
        if (g == gstar) {
            const float iv = pB[0][h]       + pB[1][h]       + xgl[cur][h];
            const float fv = pB[0][128+h]   + pB[1][128+h]   + xgl[cur][128+h];
            const float ov = pB[0][256+h]   + pB[1][256+h]   + xgl[cur][256+h];
            const float gv = pB[0][384+h]   + pB[1][384+h]   + xgl[cur][384+h];
            const float si = 1.f / (1.f + expf(-iv));
            const float sf = 1.f / (1.f + expf(-fv));
            const float so = 1.f / (1.f + expf(-ov));
            const float tg = tanhf(gv);
            const float cn = m * (sf * csum[h] + si * tg);
            const float hn = m * (so * tanhf(cn));
            const int kt = t - 25 * gstar;
            #pragma unroll
            for (int k = 0; k < 25; ++k) if (k == kt) hreg[k] = hn;
            c_lds[h][t] = cn;
            hmacc = fmaf(m, hn, hmacc);
        }
        len += m;
        // next phase A reads topoS[nxt] (written before bar C) and c_lds (same-
        // thread). part_/hsum/csum/pB rewrites are >=1 barrier from their readers.
    }

    part_h[g][h] = hmacc;     // unique slot per thread
    __syncthreads();
    if (tid < HID) {
        float s = 0.f;
        #pragma unroll
        for (int gg = 0; gg < 8; ++gg) s += part_h[gg][tid];
        hmT[(size_t)tid * NBATCH + n] = s / len;   // transposed for k3
    }
}

// ---------------- Kernel 3: out = h_mean @ W_out + b_out  (k-outer matvec) ----------------
// 512 thr: v = column; acc[32] rows; Wout coalesced, hmT row-slice via s_load.
__global__ __launch_bounds__(512) void k3_out(
    const float* __restrict__ hmT,     // (H, N)
    const float* __restrict__ Wout,    // (H, V)
    const float* __restrict__ bout,    // (V)
    float* __restrict__ out)           // (N, V)
{
    const int tid = threadIdx.x;
    const int v = blockIdx.x * 512 + tid;
    const int r0 = blockIdx.y * 32;
    const int vc = v < VOC ? v : VOC - 1;

    float acc[32];
    #pragma unroll
    for (int r = 0; r < 32; ++r) acc[r] = 0.f;

    #pragma unroll 2
    for (int k = 0; k < HID; ++k) {
        const float wv = Wout[(size_t)k * VOC + vc];   // coalesced vector load
        const float* hr = hmT + k * NBATCH + r0;       // uniform -> s_load
        #pragma unroll
        for (int r = 0; r < 32; ++r) acc[r] = fmaf(hr[r], wv, acc[r]);
    }
    const float bv = bout[vc];
    if (v < VOC) {
        for (int r = 0; r < 32; ++r)
            out[(size_t)(r0 + r) * VOC + v] = acc[r] + bv;
    }
}

extern "C" void kernel_launch(void* const* d_in, const int* in_sizes, int n_in,
                              void* d_out, int out_size, void* d_ws, size_t ws_size,
                              hipStream_t stream) {
    const int*   seq  = (const int*)d_in[0];     // (T,N) int32
    const float* msk  = (const float*)d_in[1];   // (T,N)
    const float* topo = (const float*)d_in[2];   // (T,N,T)
    const float* W    = (const float*)d_in[3];   // (H,4H)
    const float* U    = (const float*)d_in[4];   // (H,4H)
    const float* b    = (const float*)d_in[5];   // (4H)
    const float* ET   = (const float*)d_in[6];   // (V,H)
    const float* Wout = (const float*)d_in[7];   // (H,V)
    const float* bout = (const float*)d_in[8];   // (V)
    float* out = (float*)d_out;

    float* XW  = (float*)d_ws;                                   // 102.4 MB
    float* hmT = (float*)((char*)d_ws + (size_t)VOC * G4 * sizeof(float)); // +128 KB

    kxw<<<(VOC + 31) / 32, 512, 0, stream>>>(ET, W, b, XW);
    k2_recur<<<NBATCH, 1024, 0, stream>>>(topo, msk, U, seq, XW, hmT);
    k3_out<<<dim3(98, 8), 512, 0, stream>>>(hmT, Wout, bout, out);
}

// Round 7
// 856.338 us; speedup vs baseline: 3.1441x; 1.0704x over previous
//
#include <hip/hip_runtime.h>
#include <hip/hip_bf16.h>

#define TT 200
#define NBATCH 256
#define HID 128
#define G4 512
#define VOC 50000

// R9/R10 design notes:
// - R8 measured: total 916.6us, k2 687us (VGPR 64, FETCH 81MB, VALUBusy 30%,
//   0 bank conflicts). LDS-pipe model closes at ~7500/8240 cyc per step, of
//   which ~4300 cyc are WAVE-UNIFORM BROADCAST reads (topo tp4: 1250, hsum
//   b128 x16: 3070) -- every wave re-reads the same floats through the one
//   shared LDS pipe.
// - R9 single change: broadcast-LDS -> lane-distribute + v_readlane. Each wave
//   does ONE ds_read_b32 (hsum[kh*64+lane] / topoS[g][lane&31]) then extracts
//   element k as an SGPR via __builtin_amdgcn_readlane(val,k) (compile-time k).
//   Moves ~4200 cyc off the serialized LDS pipe onto parallel per-SIMD VALU.
//   Persistent regs (ucol/hreg) and loop structure UNTOUCHED (R6/R7 spill
//   trigger avoided). Tripwire: FETCH_SIZE must stay ~81MB.
// - R10: resubmission of R9 (broker timeout, never measured). Audited:
//   wave-uniformity of g/kh, readlane exec semantics, bank patterns, SGPR use.
// - Banked: c_lds[h][209] scalar reads are conflict-free and per-lane distinct
//   (already 8-way distributed); don't vectorize, don't readlane them.

#define RL(v, l) __uint_as_float((unsigned)__builtin_amdgcn_readlane((int)__float_as_uint(v), (l)))

// ---------------- Kernel XW: XW = ET @ W + b  (50000 x 512) ----------------
// 512 thr: 32 rows x 512 cols per block. jq=tid&127 -> cols 4jq..4jq+3,
// rg=tid>>7 -> rows 8rg..8rg+8. ET tile (16KB) staged once, then pure compute.
__global__ __launch_bounds__(512) void kxw(
    const float* __restrict__ ET,       // (V, H)
    const float* __restrict__ W,        // (H, 4H)
    const float* __restrict__ b,        // (4H)
    float* __restrict__ XW)             // (V, 4H)
{
    const int tid = threadIdx.x;
    const int jq = tid & 127;
    const int j0 = jq * 4;
    const int rg = tid >> 7;            // 0..3, wave-uniform
    const int rb = blockIdx.x * 32;

    __shared__ __align__(16) float et[32][HID];   // 16 KB

    // stage ET tile: 4096 floats, thread loads 8 consecutive (2x float4)
    {
        const int bse = tid * 8;
        const int r = bse >> 7, c = bse & 127;
        int row = rb + r; row = row < VOC ? row : VOC - 1;
        const float4* src = (const float4*)(ET + (size_t)row * HID + c);
        float4 v0 = src[0], v1 = src[1];
        *((float4*)&et[r][c])     = v0;
        *((float4*)&et[r][c + 4]) = v1;
    }
    __syncthreads();

    float acc[8][4];
    #pragma unroll
    for (int r = 0; r < 8; ++r) {
        acc[r][0] = 0.f; acc[r][1] = 0.f; acc[r][2] = 0.f; acc[r][3] = 0.f;
    }

    const float4* W4 = (const float4*)W;     // W[k][j0..j0+3] = W4[k*128 + jq]
    #pragma unroll 2
    for (int k4 = 0; k4 < 32; ++k4) {
        const float4 w0 = W4[(size_t)(4 * k4 + 0) * 128 + jq];
        const float4 w1 = W4[(size_t)(4 * k4 + 1) * 128 + jq];
        const float4 w2 = W4[(size_t)(4 * k4 + 2) * 128 + jq];
        const float4 w3 = W4[(size_t)(4 * k4 + 3) * 128 + jq];
        #pragma unroll
        for (int r = 0; r < 8; ++r) {
            const float4 e4 = *(const float4*)&et[rg * 8 + r][4 * k4];  // broadcast
            acc[r][0] = fmaf(e4.x, w0.x, acc[r][0]);
            acc[r][0] = fmaf(e4.y, w1.x, acc[r][0]);
            acc[r][0] = fmaf(e4.z, w2.x, acc[r][0]);
            acc[r][0] = fmaf(e4.w, w3.x, acc[r][0]);
            acc[r][1] = fmaf(e4.x, w0.y, acc[r][1]);
            acc[r][1] = fmaf(e4.y, w1.y, acc[r][1]);
            acc[r][1] = fmaf(e4.z, w2.y, acc[r][1]);
            acc[r][1] = fmaf(e4.w, w3.y, acc[r][1]);
            acc[r][2] = fmaf(e4.x, w0.z, acc[r][2]);
            acc[r][2] = fmaf(e4.y, w1.z, acc[r][2]);
            acc[r][2] = fmaf(e4.z, w2.z, acc[r][2]);
            acc[r][2] = fmaf(e4.w, w3.z, acc[r][2]);
            acc[r][3] = fmaf(e4.x, w0.w, acc[r][3]);
            acc[r][3] = fmaf(e4.y, w1.w, acc[r][3]);
            acc[r][3] = fmaf(e4.z, w2.w, acc[r][3]);
            acc[r][3] = fmaf(e4.w, w3.w, acc[r][3]);
        }
    }

    const float4 bj = *(const float4*)&b[j0];
    #pragma unroll
    for (int r = 0; r < 8; ++r) {
        const int row = rb + rg * 8 + r;
        if (row < VOC) {
            float4 o;
            o.x = acc[r][0] + bj.x; o.y = acc[r][1] + bj.y;
            o.z = acc[r][2] + bj.z; o.w = acc[r][3] + bj.w;
            *(float4*)&XW[(size_t)row * G4 + j0] = o;
        }
    }
}

// ---------------- Kernel 2: recurrence, one 1024-thr block per n ----------------
// R8 structure with broadcast->readlane at two sites (phase A topo, phase B hsum).
// h history in regs (hreg[25], group g=tid>>7 owns rows [25g,25g+25)),
// c history in LDS (c_lds[h][209], pad 209 -> conflict-free),
// U in regs (ucol[64], K-half kh=tid>>9). 3 barriers/step.
__global__ __launch_bounds__(1024) void k2_recur(
    const float* __restrict__ topo,     // (T, N, T)
    const float* __restrict__ mask,     // (T, N)
    const float* __restrict__ U,        // (H, 4H)
    const int*   __restrict__ seq,      // (T, N)
    const float* __restrict__ XW,       // (V, 4H)
    float* __restrict__ hmT)            // (H, N) transposed h_mean
{
    const int n    = blockIdx.x;
    const int tid  = threadIdx.x;
    const int g    = __builtin_amdgcn_readfirstlane(tid >> 7);   // 0..7
    const int h    = tid & 127;
    const int kh   = __builtin_amdgcn_readfirstlane(tid >> 9);   // 0..1
    const int j    = tid & 511;
    const int lane = tid & 63;

    __shared__ float c_lds[HID][209];                 // 104.5 KB, c_lds[h][t']
    __shared__ __align__(16) float topoS[2][8][32];   // double-buffered topo row
    __shared__ float part_h[8][HID];
    __shared__ float part_c[8][HID];
    __shared__ __align__(16) float hsum[HID];
    __shared__ float csum[HID];
    __shared__ float pB[2][G4];
    __shared__ float xgl[2][G4];
    __shared__ int   seq_l[TT];
    __shared__ float mask_l[TT];

    float ucol[64];
    #pragma unroll
    for (int kk = 0; kk < 64; ++kk) ucol[kk] = U[(size_t)(kh * 64 + kk) * G4 + j];

    float hreg[25];
    #pragma unroll
    for (int k = 0; k < 25; ++k) hreg[k] = 0.f;
    for (int i = tid; i < HID * 209; i += 1024) (&c_lds[0][0])[i] = 0.f;

    // one-time preload: per-n sequence + mask rows (kills per-step s_load chain)
    if (tid < TT) {
        seq_l[tid]  = seq[tid * NBATCH + n];
        mask_l[tid] = mask[tid * NBATCH + n];
    }
    // prologue stage for t=0 (addresses straight from global, uniform)
    if (tid < G4) {
        xgl[0][tid] = XW[(size_t)seq[n] * G4 + tid];
    } else if (tid < 768) {
        const int tt = tid - 512;
        const int gg = tt >> 5, ii = tt & 31;
        topoS[0][gg][ii] = (ii < 25)
            ? topo[(size_t)n * TT + 25 * gg + ii] : 0.f;   // t=0 row
    }

    float hmacc = 0.f, len = 0.f;
    __syncthreads();

    for (int t = 0; t < TT; ++t) {
        const int cur = t & 1, nxt = cur ^ 1;

        // ---- issue prefetch for step t+1 (registers; committed before bar C) ----
        const int tn = (t + 1 < TT) ? t + 1 : t;
        float pf = 0.f;
        if (tid < G4) {
            pf = XW[(size_t)seq_l[tn] * G4 + tid];
        } else if (tid < 768) {
            const int tt = tid - 512;
            const int gg = tt >> 5, ii = tt & 31;
            pf = (ii < 25)
                ? topo[((size_t)tn * NBATCH + n) * TT + 25 * gg + ii] : 0.f;
        }
        const float m = mask_l[t];

        // ---- phase A: topo row via lane-distribute + readlane (1 ds_read_b32
        //      per wave instead of 6 b128 broadcast); h from regs, c from LDS ----
        const float tval = topoS[cur][g][lane & 31];   // lane k<25 holds topo[k]
        float ah0 = 0.f, ah1 = 0.f, ac0 = 0.f, ac1 = 0.f;
        const int base = 25 * g;
        const float* crow = &c_lds[h][0];
        #pragma unroll
        for (int kk = 0; kk < 6; ++kk) {
            if (base + 4 * kk < t) {        // perf guard only; data is 0 beyond t
                const float t0 = RL(tval, 4 * kk + 0);
                const float t1 = RL(tval, 4 * kk + 1);
                const float t2 = RL(tval, 4 * kk + 2);
                const float t3 = RL(tval, 4 * kk + 3);
                ah0 = fmaf(t0, hreg[4*kk+0], ah0);
                ac0 = fmaf(t0, crow[base+4*kk+0], ac0);
                ah1 = fmaf(t1, hreg[4*kk+1], ah1);
                ac1 = fmaf(t1, crow[base+4*kk+1], ac1);
                ah0 = fmaf(t2, hreg[4*kk+2], ah0);
                ac0 = fmaf(t2, crow[base+4*kk+2], ac0);
                ah1 = fmaf(t3, hreg[4*kk+3], ah1);
                ac1 = fmaf(t3, crow[base+4*kk+3], ac1);
            }
        }
        if (base + 24 < t) {
            const float tpl = RL(tval, 24);
            ah0 = fmaf(tpl, hreg[24], ah0);
            ac0 = fmaf(tpl, crow[base+24], ac0);
        }
        part_h[g][h] = ah0 + ah1;
        part_c[g][h] = ac0 + ac1;
        __syncthreads();                                        // (A)

        if (tid < HID) {
            float s = 0.f;
            #pragma unroll
            for (int gg = 0; gg < 8; ++gg) s += part_h[gg][tid];
            hsum[tid] = s;
        } else if (tid < 2 * HID) {
            const int hh = tid - HID;
            float s = 0.f;
            #pragma unroll
            for (int gg = 0; gg < 8; ++gg) s += part_c[gg][hh];
            csum[hh] = s;
        }
        __syncthreads();                                        // (B)

        // ---- phase B: pB[kh][j] = hsum[kh-half] . U-half column, hsum via
        //      lane-distribute + readlane (1 ds_read_b32/wave instead of 16 b128) ----
        {
            const float hval = hsum[kh * 64 + lane];   // lane k holds hsum[kh*64+k]
            float a0 = 0.f, a1 = 0.f, a2 = 0.f, a3 = 0.f;
            #pragma unroll
            for (int q = 0; q < 16; ++q) {
                a0 = fmaf(RL(hval, 4*q+0), ucol[4*q+0], a0);
                a1 = fmaf(RL(hval, 4*q+1), ucol[4*q+1], a1);
                a2 = fmaf(RL(hval, 4*q+2), ucol[4*q+2], a2);
                a3 = fmaf(RL(hval, 4*q+3), ucol[4*q+3], a3);
            }
            pB[kh][j] = (a0 + a1) + (a2 + a3);
        }
        // commit prefetch to the nxt buffers (separated from next phase A by bar C)
        if (tid < G4) {
            xgl[nxt][tid] = pf;
        } else if (tid < 768) {
            const int tt = tid - 512;
            topoS[nxt][tt >> 5][tt & 31] = pf;
        }
        __syncthreads();                                        // (C)

        // ---- cell: owning group g* = t/25 (wave-uniform branch) ----
        const int gstar = t / 25;
        if (g == gstar) {
            const float iv = pB[0][h]       + pB[1][h]       + xgl[cur][h];
            const float fv = pB[0][128+h]   + pB[1][128+h]   + xgl[cur][128+h];
            const float ov = pB[0][256+h]   + pB[1][256+h]   + xgl[cur][256+h];
            const float gv = pB[0][384+h]   + pB[1][384+h]   + xgl[cur][384+h];
            const float si = 1.f / (1.f + expf(-iv));
            const float sf = 1.f / (1.f + expf(-fv));
            const float so = 1.f / (1.f + expf(-ov));
            const float tg = tanhf(gv);
            const float cn = m * (sf * csum[h] + si * tg);
            const float hn = m * (so * tanhf(cn));
            const int kt = t - 25 * gstar;
            #pragma unroll
            for (int k = 0; k < 25; ++k) if (k == kt) hreg[k] = hn;
            c_lds[h][t] = cn;
            hmacc = fmaf(m, hn, hmacc);
        }
        len += m;
        // next phase A reads topoS[nxt] (written before bar C) and c_lds (same-
        // thread). part_/hsum/csum/pB rewrites are >=1 barrier from their readers.
    }

    part_h[g][h] = hmacc;     // unique slot per thread
    __syncthreads();
    if (tid < HID) {
        float s = 0.f;
        #pragma unroll
        for (int gg = 0; gg < 8; ++gg) s += part_h[gg][tid];
        hmT[(size_t)tid * NBATCH + n] = s / len;   // transposed for k3
    }
}

// ---------------- Kernel 3: out = h_mean @ W_out + b_out  (k-outer matvec) ----------------
// 512 thr: v = column; acc[32] rows; Wout coalesced, hmT row-slice via s_load.
__global__ __launch_bounds__(512) void k3_out(
    const float* __restrict__ hmT,     // (H, N)
    const float* __restrict__ Wout,    // (H, V)
    const float* __restrict__ bout,    // (V)
    float* __restrict__ out)           // (N, V)
{
    const int tid = threadIdx.x;
    const int v = blockIdx.x * 512 + tid;
    const int r0 = blockIdx.y * 32;
    const int vc = v < VOC ? v : VOC - 1;

    float acc[32];
    #pragma unroll
    for (int r = 0; r < 32; ++r) acc[r] = 0.f;

    #pragma unroll 2
    for (int k = 0; k < HID; ++k) {
        const float wv = Wout[(size_t)k * VOC + vc];   // coalesced vector load
        const float* hr = hmT + k * NBATCH + r0;       // uniform -> s_load
        #pragma unroll
        for (int r = 0; r < 32; ++r) acc[r] = fmaf(hr[r], wv, acc[r]);
    }
    const float bv = bout[vc];
    if (v < VOC) {
        for (int r = 0; r < 32; ++r)
            out[(size_t)(r0 + r) * VOC + v] = acc[r] + bv;
    }
}

extern "C" void kernel_launch(void* const* d_in, const int* in_sizes, int n_in,
                              void* d_out, int out_size, void* d_ws, size_t ws_size,
                              hipStream_t stream) {
    const int*   seq  = (const int*)d_in[0];     // (T,N) int32
    const float* msk  = (const float*)d_in[1];   // (T,N)
    const float* topo = (const float*)d_in[2];   // (T,N,T)
    const float* W    = (const float*)d_in[3];   // (H,4H)
    const float* U    = (const float*)d_in[4];   // (H,4H)
    const float* b    = (const float*)d_in[5];   // (4H)
    const float* ET   = (const float*)d_in[6];   // (V,H)
    const float* Wout = (const float*)d_in[7];   // (H,V)
    const float* bout = (const float*)d_in[8];   // (V)
    float* out = (float*)d_out;

    float* XW  = (float*)d_ws;                                   // 102.4 MB
    float* hmT = (float*)((char*)d_ws + (size_t)VOC * G4 * sizeof(float)); // +128 KB

    kxw<<<(VOC + 31) / 32, 512, 0, stream>>>(ET, W, b, XW);
    k2_recur<<<NBATCH, 1024, 0, stream>>>(topo, msk, U, seq, XW, hmT);
    k3_out<<<dim3(98, 8), 512, 0, stream>>>(hmT, Wout, bout, out);
}